// Round 1
// baseline (124.082 us; speedup 1.0000x reference)
//
#include <hip/hip_runtime.h>
#include <hip/hip_bf16.h>
#include <stdint.h>

// ---------------- problem constants ----------------
#define BATCH  4096
#define IN_DIM 1024
#define HS     1024
#define K_DIM  2048                 // IN + HS
#define N_DIM  4096                 // 4 gates * HS
#define BM 128
#define BN 128
#define BK 64
#define NKT (K_DIM / BK)            // 32 K-tiles
#define TILE_BYTES (BM * BK * 2)    // 16384 B per staged tile

typedef __bf16 bf16x8 __attribute__((ext_vector_type(8)));
typedef float  f32x4  __attribute__((ext_vector_type(4)));

// ---------------- helpers ----------------
__device__ __forceinline__ unsigned short f2bf(float f) {
    union { float f; uint32_t u; } a; a.f = f;
    uint32_t r = a.u + 0x7FFF + ((a.u >> 16) & 1);   // RNE
    return (unsigned short)(r >> 16);
}
__device__ __forceinline__ uint32_t pk2(float a, float b) {
    return (uint32_t)f2bf(a) | ((uint32_t)f2bf(b) << 16);
}

// global(per-lane src) -> LDS(wave-uniform base + lane*16), 16B per lane
__device__ __forceinline__ void load16_lds(const void* g, void* l) {
    __builtin_amdgcn_global_load_lds(
        (const __attribute__((address_space(1))) uint32_t*)g,
        (__attribute__((address_space(3))) uint32_t*)(uintptr_t)l,
        16, 0, 0);
}

__device__ __forceinline__ float sigf(float x) { return 1.0f / (1.0f + __expf(-x)); }

// ---------------- kernel 1: pack A=[x|h], B=gate weights, fp32->bf16,
// tile-contiguous (16KB per (tile,ktile) chunk) with inverse XOR-swizzle
// baked into the gather so linear LDS staging yields the swizzled layout.
__global__ void pack_kernel(const float* __restrict__ x, const float* __restrict__ h,
                            const float* __restrict__ Wix, const float* __restrict__ Wfx,
                            const float* __restrict__ Wgx, const float* __restrict__ Wox,
                            const float* __restrict__ Wih, const float* __restrict__ Wfh,
                            const float* __restrict__ Wgh, const float* __restrict__ Woh,
                            uint4* __restrict__ Apk, uint4* __restrict__ Bpk)
{
    int t = blockIdx.x * blockDim.x + threadIdx.x;     // 0 .. 2M-1
    const int NCHUNK = (BATCH * K_DIM) / 8;            // 1,048,576 chunks / matrix
    bool isB = t >= NCHUNK;
    int ci = isB ? (t - NCHUNK) : t;

    int cb  = ci & 7;              // 16B chunk within row (8 bf16)
    int row = (ci >> 3) & 127;     // row within tile
    int kt  = (ci >> 10) & 31;     // K-tile
    int bt  = ci >> 15;            // M- or N-tile index, 0..31

    // inverse swizzle: chunk cb of LDS row holds source chunk cb ^ (row&7)
    int k0 = kt * BK + ((cb ^ (row & 7)) << 3);        // source k element, %8==0
    int gr = bt * 128 + row;                           // global m or n

    const float* src;
    if (!isB) {
        src = (k0 < IN_DIM) ? (x + (size_t)gr * IN_DIM + k0)
                            : (h + (size_t)gr * HS + (k0 - IN_DIM));
    } else {
        int q = gr >> 10;          // gate (blocked layout: n = q*1024 + u)
        int u = gr & 1023;
        const float* Wq = (k0 < IN_DIM)
            ? ((q == 0) ? Wix : (q == 1) ? Wfx : (q == 2) ? Wgx : Wox)
            : ((q == 0) ? Wih : (q == 1) ? Wfh : (q == 2) ? Wgh : Woh);
        int kk = (k0 < IN_DIM) ? k0 : (k0 - IN_DIM);
        src = Wq + (size_t)u * 1024 + kk;
    }
    float4 v0 = ((const float4*)src)[0];
    float4 v1 = ((const float4*)src)[1];
    uint4 o;
    o.x = pk2(v0.x, v0.y); o.y = pk2(v0.z, v0.w);
    o.z = pk2(v1.x, v1.y); o.w = pk2(v1.z, v1.w);
    (isB ? Bpk : Apk)[ci] = o;
}

// ---------------- kernel 2: z = A * B^T  (bf16 MFMA, fp32 out) ----------------
// m97 structure: 128x128 tile, BK=64, 4 waves 2x2, 4x4 16x16x32 fragments/wave.
__global__ void __launch_bounds__(256)
gemm_kernel(const char* __restrict__ Apk, const char* __restrict__ Bpk,
            float* __restrict__ z)
{
    __shared__ uint4 lds4[(2 * TILE_BYTES) / 16];      // 32 KB: A then B
    char* ldsA = (char*)lds4;
    char* ldsB = (char*)lds4 + TILE_BYTES;

    const int tid  = threadIdx.x;
    const int lane = tid & 63;
    const int wid  = tid >> 6;
    const int wm   = wid >> 1;       // 0..1
    const int wn   = wid & 1;        // 0..1
    const int bn   = blockIdx.x;     // 0..31
    const int bm   = blockIdx.y;     // 0..31

    const char* gA = Apk ? (const char*)Apk + (size_t)bm * NKT * TILE_BYTES : nullptr;
    const char* gB = (const char*)Bpk + (size_t)bn * NKT * TILE_BYTES;

    const int fr = lane & 15;        // row within fragment (m or n)
    const int kg = lane >> 4;        // k group (8 contiguous k elems)

    f32x4 acc[4][4] = {};

    for (int kt = 0; kt < NKT; ++kt) {
        __syncthreads();             // previous compute done before overwrite
        const char* sa = gA + (size_t)kt * TILE_BYTES + wid * 1024 + lane * 16;
        const char* sb = gB + (size_t)kt * TILE_BYTES + wid * 1024 + lane * 16;
        #pragma unroll
        for (int i = 0; i < 4; ++i) {                 // chunk = i*4 + wid
            load16_lds(sa + i * 4096, ldsA + (i * 4 + wid) * 1024);
            load16_lds(sb + i * 4096, ldsB + (i * 4 + wid) * 1024);
        }
        __syncthreads();             // compiler drains vmcnt before s_barrier

        #pragma unroll
        for (int ks = 0; ks < 2; ++ks) {
            bf16x8 a[4], b[4];
            #pragma unroll
            for (int i = 0; i < 4; ++i) {
                int rowA = wm * 64 + i * 16 + fr;
                int kbA  = (ks * 64 + kg * 16) ^ ((rowA & 7) << 4);
                a[i] = *(const bf16x8*)(ldsA + rowA * 128 + kbA);
                int rowB = wn * 64 + i * 16 + fr;
                int kbB  = (ks * 64 + kg * 16) ^ ((rowB & 7) << 4);
                b[i] = *(const bf16x8*)(ldsB + rowB * 128 + kbB);
            }
            #pragma unroll
            for (int i = 0; i < 4; ++i)
                #pragma unroll
                for (int j = 0; j < 4; ++j)
                    acc[i][j] = __builtin_amdgcn_mfma_f32_16x16x32_bf16(
                        a[i], b[j], acc[i][j], 0, 0, 0);
        }
    }

    // C/D layout (m89-verified): col = lane&15, row = (lane>>4)*4 + reg
    const int row0 = bm * BM + wm * 64;
    const int col0 = bn * BN + wn * 64;
    #pragma unroll
    for (int i = 0; i < 4; ++i)
        #pragma unroll
        for (int j = 0; j < 4; ++j) {
            int col = col0 + j * 16 + fr;
            #pragma unroll
            for (int r = 0; r < 4; ++r) {
                int row = row0 + i * 16 + kg * 4 + r;
                z[(size_t)row * N_DIM + col] = acc[i][j][r];
            }
        }
}

// ---------------- kernel 3: elementwise LSTM gates ----------------
__global__ void __launch_bounds__(256)
epilogue_kernel(const float* __restrict__ z, const float* __restrict__ c,
                const float* __restrict__ bix, const float* __restrict__ bfx,
                const float* __restrict__ bgx, const float* __restrict__ box_,
                const float* __restrict__ bih, const float* __restrict__ bfh,
                const float* __restrict__ bgh, const float* __restrict__ boh,
                float* __restrict__ out)
{
    int t = blockIdx.x * blockDim.x + threadIdx.x;     // 0 .. 1M-1
    int e = t << 2;                                    // element base (x4)
    int m = e >> 10;
    int u = e & 1023;
    size_t zrow = (size_t)m * N_DIM;

    union F4 { float4 v; float a[4]; };
    F4 zi, zf, zg, zo, cc, b_i, b_f, b_g, b_o, hx, hh, cn4, hn4;
    zi.v = *(const float4*)&z[zrow + 0 * HS + u];
    zf.v = *(const float4*)&z[zrow + 1 * HS + u];
    zg.v = *(const float4*)&z[zrow + 2 * HS + u];
    zo.v = *(const float4*)&z[zrow + 3 * HS + u];
    cc.v = *(const float4*)&c[e];
    hx.v = *(const float4*)&bix[u]; hh.v = *(const float4*)&bih[u];
    b_i.v = make_float4(hx.a[0]+hh.a[0], hx.a[1]+hh.a[1], hx.a[2]+hh.a[2], hx.a[3]+hh.a[3]);
    hx.v = *(const float4*)&bfx[u]; hh.v = *(const float4*)&bfh[u];
    b_f.v = make_float4(hx.a[0]+hh.a[0], hx.a[1]+hh.a[1], hx.a[2]+hh.a[2], hx.a[3]+hh.a[3]);
    hx.v = *(const float4*)&bgx[u]; hh.v = *(const float4*)&bgh[u];
    b_g.v = make_float4(hx.a[0]+hh.a[0], hx.a[1]+hh.a[1], hx.a[2]+hh.a[2], hx.a[3]+hh.a[3]);
    hx.v = *(const float4*)&box_[u]; hh.v = *(const float4*)&boh[u];
    b_o.v = make_float4(hx.a[0]+hh.a[0], hx.a[1]+hh.a[1], hx.a[2]+hh.a[2], hx.a[3]+hh.a[3]);

    #pragma unroll
    for (int j = 0; j < 4; ++j) {
        float iv = sigf(zi.a[j] + b_i.a[j]);
        float fv = sigf(zf.a[j] + b_f.a[j]);
        float gv = tanhf(zg.a[j] + b_g.a[j]);
        float ov = sigf(zo.a[j] + b_o.a[j]);
        float cn = fv * cc.a[j] + iv * gv;
        cn4.a[j] = cn;
        hn4.a[j] = ov * tanhf(cn);
    }
    *(float4*)&out[e] = hn4.v;                                     // h_new
    *(float4*)&out[(size_t)BATCH * HS + e] = cn4.v;                // c_new
}

// ---------------- launcher ----------------
extern "C" void kernel_launch(void* const* d_in, const int* in_sizes, int n_in,
                              void* d_out, int out_size, void* d_ws, size_t ws_size,
                              hipStream_t stream)
{
    const float* x   = (const float*)d_in[0];
    const float* h   = (const float*)d_in[1];
    const float* c   = (const float*)d_in[2];
    const float* Wix = (const float*)d_in[3];  const float* bix = (const float*)d_in[4];
    const float* Wfx = (const float*)d_in[5];  const float* bfx = (const float*)d_in[6];
    const float* Wgx = (const float*)d_in[7];  const float* bgx = (const float*)d_in[8];
    const float* Wox = (const float*)d_in[9];  const float* box_ = (const float*)d_in[10];
    const float* Wih = (const float*)d_in[11]; const float* bih = (const float*)d_in[12];
    const float* Wfh = (const float*)d_in[13]; const float* bfh = (const float*)d_in[14];
    const float* Wgh = (const float*)d_in[15]; const float* bgh = (const float*)d_in[16];
    const float* Woh = (const float*)d_in[17]; const float* boh = (const float*)d_in[18];

    char* ws = (char*)d_ws;
    uint4* Apk = (uint4*)ws;                                   // 16 MB
    uint4* Bpk = (uint4*)(ws + (size_t)16 * 1024 * 1024);      // 16 MB
    float* z   = (float*)(ws + (size_t)32 * 1024 * 1024);      // 64 MB

    pack_kernel<<<8192, 256, 0, stream>>>(x, h, Wix, Wfx, Wgx, Wox,
                                          Wih, Wfh, Wgh, Woh, Apk, Bpk);
    gemm_kernel<<<dim3(32, 32), 256, 0, stream>>>((const char*)Apk, (const char*)Bpk, z);
    epilogue_kernel<<<4096, 256, 0, stream>>>(z, c, bix, bfx, bgx, box_,
                                              bih, bfh, bgh, boh, (float*)d_out);
}

// Round 2
// 102.016 us; speedup vs baseline: 1.2163x; 1.2163x over previous
//
#include <hip/hip_runtime.h>
#include <hip/hip_bf16.h>
#include <stdint.h>

// ---------------- problem constants ----------------
#define BATCH  4096
#define IN_DIM 1024
#define HS     1024
#define K_DIM  2048                 // IN + HS
#define N_DIM  4096                 // 4 gates * HS
#define BK 64
#define NKT (K_DIM / BK)            // 32 K-tiles
#define HALF_BYTES 16384            // 128 rows x 64 cols x 2B
#define TPB_BYTES  (NKT * HALF_BYTES)   // bytes per 128-row panel, all K

typedef __bf16 bf16x8 __attribute__((ext_vector_type(8)));
typedef float  f32x4  __attribute__((ext_vector_type(4)));

// ---------------- helpers ----------------
__device__ __forceinline__ unsigned short f2bf(float f) {
    union { float f; uint32_t u; } a; a.f = f;
    uint32_t r = a.u + 0x7FFF + ((a.u >> 16) & 1);   // RNE
    return (unsigned short)(r >> 16);
}
__device__ __forceinline__ uint32_t pk2(float a, float b) {
    return (uint32_t)f2bf(a) | ((uint32_t)f2bf(b) << 16);
}

// global(per-lane src) -> LDS(wave-uniform base + lane*16), 16B per lane
__device__ __forceinline__ void load16_lds(const void* g, void* l) {
    __builtin_amdgcn_global_load_lds(
        (const __attribute__((address_space(1))) uint32_t*)g,
        (__attribute__((address_space(3))) uint32_t*)(uintptr_t)l,
        16, 0, 0);
}

// stage one 16KB half-tile: 512 threads x 16B x 2 rounds
__device__ __forceinline__ void stage16k(const char* g, char* l, int wid, int lane) {
    load16_lds(g + wid * 1024 + lane * 16,        l + wid * 1024);
    load16_lds(g + 8192 + wid * 1024 + lane * 16, l + 8192 + wid * 1024);
}

__device__ __forceinline__ float sigf(float x) { return 1.0f / (1.0f + __expf(-x)); }

#define BAR()   __builtin_amdgcn_s_barrier()
#define LGKM0() do { asm volatile("s_waitcnt lgkmcnt(0)" ::: "memory"); \
                     __builtin_amdgcn_sched_barrier(0); } while (0)
#define PRIO(x) __builtin_amdgcn_s_setprio(x)

// ---------------- kernel 1: pack (UNCHANGED from round 1, known-good) -------
__global__ void pack_kernel(const float* __restrict__ x, const float* __restrict__ h,
                            const float* __restrict__ Wix, const float* __restrict__ Wfx,
                            const float* __restrict__ Wgx, const float* __restrict__ Wox,
                            const float* __restrict__ Wih, const float* __restrict__ Wfh,
                            const float* __restrict__ Wgh, const float* __restrict__ Woh,
                            uint4* __restrict__ Apk, uint4* __restrict__ Bpk)
{
    int t = blockIdx.x * blockDim.x + threadIdx.x;     // 0 .. 2M-1
    const int NCHUNK = (BATCH * K_DIM) / 8;            // 1,048,576 chunks / matrix
    bool isB = t >= NCHUNK;
    int ci = isB ? (t - NCHUNK) : t;

    int cb  = ci & 7;              // 16B chunk within row (8 bf16)
    int row = (ci >> 3) & 127;     // row within 128-row panel
    int kt  = (ci >> 10) & 31;     // K-tile
    int bt  = ci >> 15;            // 128-row panel index, 0..31

    // inverse swizzle: chunk cb of LDS row holds source chunk cb ^ (row&7)
    int k0 = kt * BK + ((cb ^ (row & 7)) << 3);        // source k element, %8==0
    int gr = bt * 128 + row;                           // global m or n

    const float* src;
    if (!isB) {
        src = (k0 < IN_DIM) ? (x + (size_t)gr * IN_DIM + k0)
                            : (h + (size_t)gr * HS + (k0 - IN_DIM));
    } else {
        int q = gr >> 10;          // gate (blocked layout: n = q*1024 + u)
        int u = gr & 1023;
        const float* Wq = (k0 < IN_DIM)
            ? ((q == 0) ? Wix : (q == 1) ? Wfx : (q == 2) ? Wgx : Wox)
            : ((q == 0) ? Wih : (q == 1) ? Wfh : (q == 2) ? Wgh : Woh);
        int kk = (k0 < IN_DIM) ? k0 : (k0 - IN_DIM);
        src = Wq + (size_t)u * 1024 + kk;
    }
    float4 v0 = ((const float4*)src)[0];
    float4 v1 = ((const float4*)src)[1];
    uint4 o;
    o.x = pk2(v0.x, v0.y); o.y = pk2(v0.z, v0.w);
    o.z = pk2(v1.x, v1.y); o.w = pk2(v1.z, v1.w);
    (isB ? Bpk : Apk)[ci] = o;
}

// ---------------- kernel 2: z = A * B^T, 256x256 tile, 8-phase schedule -----
// 8 waves (2M x 4N), per-wave 128x64 output, acc[8][4] f32x4.
// Phases per K-tile: (mh,ks) = (0,0),(0,1),(1,0),(1,1); 16 MFMA each.
// Staging: p1/p2 -> A halves of tile kt+1 (other buffer);
//          p3/p4 -> B halves of tile kt+2 (current buffer's B slots,
//          safe: B was register-read in p1/p2, barrier-separated).
// vmcnt(4) once per K-tile at p4 (counted, never 0 until the tail).
__global__ void __launch_bounds__(512, 2)
gemm_kernel(const char* __restrict__ Apk, const char* __restrict__ Bpk,
            float* __restrict__ z)
{
    __shared__ uint4 lds4[131072 / 16];                // 128 KiB
    char* lds = (char*)lds4;

    const int tid  = threadIdx.x;
    const int lane = tid & 63;
    const int wid  = tid >> 6;       // 0..7
    const int wm   = wid >> 2;       // 0..1
    const int wn   = wid & 3;        // 0..3
    const int fr   = lane & 15;
    const int kg   = lane >> 4;

    // XCD-aware bijective swizzle: 256 blocks, 8 XCDs, 32 blocks/XCD chunk
    const int phys = blockIdx.x;
    const int virt = (phys & 7) * 32 + (phys >> 3);
    const int bn   = virt & 15;
    const int bm   = virt >> 4;

    const char* gA = Apk + (size_t)(bm * 2) * TPB_BYTES;   // halves: panel bm*2+h
    const char* gB = Bpk + (size_t)(bn * 2) * TPB_BYTES;

    // ds_read addressing (swizzle: k-byte ^ ((row&7)<<4); row%8 == fr%8)
    const int sw  = (fr & 7) << 4;
    const int kb0 = (kg * 16) ^ sw;                 // ks=0
    const int kb1 = (64 + kg * 16) ^ sw;            // ks=1
    const int aB  = wm * HALF_BYTES + fr * 128;                           // A: half wm
    const int bB  = 32768 + (wn >> 1) * HALF_BYTES + ((wn & 1) * 64 + fr) * 128; // B

    f32x4 acc[8][4] = {};

    // ---- prologue: tile 0 (A0,A1,B0,B1) + tile 1 (B0,B1) ----
    stage16k(gA + (size_t)(0 * NKT + 0) * HALF_BYTES, lds + 0,     wid, lane);
    stage16k(gA + (size_t)(1 * NKT + 0) * HALF_BYTES, lds + 16384, wid, lane);
    stage16k(gB + (size_t)(0 * NKT + 0) * HALF_BYTES, lds + 32768, wid, lane);
    stage16k(gB + (size_t)(1 * NKT + 0) * HALF_BYTES, lds + 49152, wid, lane);
    stage16k(gB + (size_t)(0 * NKT + 1) * HALF_BYTES, lds + 65536 + 32768, wid, lane);
    stage16k(gB + (size_t)(1 * NKT + 1) * HALF_BYTES, lds + 65536 + 49152, wid, lane);
    asm volatile("s_waitcnt vmcnt(4)" ::: "memory");   // tile 0 landed; tile1-B in flight
    BAR();

    for (int kt = 0; kt < NKT; ++kt) {
        char* L  = lds + (kt & 1) * 65536;         // current buffer
        char* Ln = lds + ((kt & 1) ^ 1) * 65536;   // next buffer (A dst)
        bf16x8 a[4], b0[4], b1[4];

        // ---------- phase 1: (mh=0, ks=0) ----------
        #pragma unroll
        for (int i = 0; i < 4; ++i) a[i]  = *(const bf16x8*)(L + aB + i * 2048 + kb0);
        #pragma unroll
        for (int j = 0; j < 4; ++j) b0[j] = *(const bf16x8*)(L + bB + j * 2048 + kb0);
        if (kt + 1 < NKT)
            stage16k(gA + (size_t)(0 * NKT + kt + 1) * HALF_BYTES, Ln + 0, wid, lane);
        BAR(); LGKM0(); PRIO(1);
        #pragma unroll
        for (int i = 0; i < 4; ++i)
            #pragma unroll
            for (int j = 0; j < 4; ++j)
                acc[i][j] = __builtin_amdgcn_mfma_f32_16x16x32_bf16(a[i], b0[j], acc[i][j], 0, 0, 0);
        PRIO(0); BAR();

        // ---------- phase 2: (mh=0, ks=1) ----------
        #pragma unroll
        for (int i = 0; i < 4; ++i) a[i]  = *(const bf16x8*)(L + aB + i * 2048 + kb1);
        #pragma unroll
        for (int j = 0; j < 4; ++j) b1[j] = *(const bf16x8*)(L + bB + j * 2048 + kb1);
        if (kt + 1 < NKT)
            stage16k(gA + (size_t)(1 * NKT + kt + 1) * HALF_BYTES, Ln + 16384, wid, lane);
        BAR(); LGKM0(); PRIO(1);
        #pragma unroll
        for (int i = 0; i < 4; ++i)
            #pragma unroll
            for (int j = 0; j < 4; ++j)
                acc[i][j] = __builtin_amdgcn_mfma_f32_16x16x32_bf16(a[i], b1[j], acc[i][j], 0, 0, 0);
        PRIO(0); BAR();

        // ---------- phase 3: (mh=1, ks=0), b0 reused from registers ----------
        #pragma unroll
        for (int i = 0; i < 4; ++i) a[i] = *(const bf16x8*)(L + aB + 8192 + i * 2048 + kb0);
        if (kt + 2 < NKT)
            stage16k(gB + (size_t)(0 * NKT + kt + 2) * HALF_BYTES, L + 32768, wid, lane);
        BAR(); LGKM0(); PRIO(1);
        #pragma unroll
        for (int i = 0; i < 4; ++i)
            #pragma unroll
            for (int j = 0; j < 4; ++j)
                acc[4 + i][j] = __builtin_amdgcn_mfma_f32_16x16x32_bf16(a[i], b0[j], acc[4 + i][j], 0, 0, 0);
        PRIO(0); BAR();

        // ---------- phase 4: (mh=1, ks=1), b1 reused ----------
        #pragma unroll
        for (int i = 0; i < 4; ++i) a[i] = *(const bf16x8*)(L + aB + 8192 + i * 2048 + kb1);
        if (kt + 2 < NKT)
            stage16k(gB + (size_t)(1 * NKT + kt + 2) * HALF_BYTES, L + 49152, wid, lane);
        if (kt < NKT - 2)       asm volatile("s_waitcnt vmcnt(4)" ::: "memory");
        else if (kt == NKT - 2) asm volatile("s_waitcnt vmcnt(0)" ::: "memory");
        BAR(); LGKM0(); PRIO(1);
        #pragma unroll
        for (int i = 0; i < 4; ++i)
            #pragma unroll
            for (int j = 0; j < 4; ++j)
                acc[4 + i][j] = __builtin_amdgcn_mfma_f32_16x16x32_bf16(a[i], b1[j], acc[4 + i][j], 0, 0, 0);
        PRIO(0); BAR();
    }

    // C-write: col = lane&15, row = kg*4 + reg (m89-verified)
    const int row0 = bm * 256 + wm * 128;
    const int col0 = bn * 256 + wn * 64;
    #pragma unroll
    for (int ai = 0; ai < 8; ++ai)
        #pragma unroll
        for (int j = 0; j < 4; ++j) {
            int col = col0 + j * 16 + fr;
            #pragma unroll
            for (int r = 0; r < 4; ++r) {
                int row = row0 + ai * 16 + kg * 4 + r;
                z[(size_t)row * N_DIM + col] = acc[ai][j][r];
            }
        }
}

// ---------------- kernel 3: elementwise LSTM gates (UNCHANGED) --------------
__global__ void __launch_bounds__(256)
epilogue_kernel(const float* __restrict__ z, const float* __restrict__ c,
                const float* __restrict__ bix, const float* __restrict__ bfx,
                const float* __restrict__ bgx, const float* __restrict__ box_,
                const float* __restrict__ bih, const float* __restrict__ bfh,
                const float* __restrict__ bgh, const float* __restrict__ boh,
                float* __restrict__ out)
{
    int t = blockIdx.x * blockDim.x + threadIdx.x;     // 0 .. 1M-1
    int e = t << 2;                                    // element base (x4)
    int m = e >> 10;
    int u = e & 1023;
    size_t zrow = (size_t)m * N_DIM;

    union F4 { float4 v; float a[4]; };
    F4 zi, zf, zg, zo, cc, b_i, b_f, b_g, b_o, hx, hh, cn4, hn4;
    zi.v = *(const float4*)&z[zrow + 0 * HS + u];
    zf.v = *(const float4*)&z[zrow + 1 * HS + u];
    zg.v = *(const float4*)&z[zrow + 2 * HS + u];
    zo.v = *(const float4*)&z[zrow + 3 * HS + u];
    cc.v = *(const float4*)&c[e];
    hx.v = *(const float4*)&bix[u]; hh.v = *(const float4*)&bih[u];
    b_i.v = make_float4(hx.a[0]+hh.a[0], hx.a[1]+hh.a[1], hx.a[2]+hh.a[2], hx.a[3]+hh.a[3]);
    hx.v = *(const float4*)&bfx[u]; hh.v = *(const float4*)&bfh[u];
    b_f.v = make_float4(hx.a[0]+hh.a[0], hx.a[1]+hh.a[1], hx.a[2]+hh.a[2], hx.a[3]+hh.a[3]);
    hx.v = *(const float4*)&bgx[u]; hh.v = *(const float4*)&bgh[u];
    b_g.v = make_float4(hx.a[0]+hh.a[0], hx.a[1]+hh.a[1], hx.a[2]+hh.a[2], hx.a[3]+hh.a[3]);
    hx.v = *(const float4*)&box_[u]; hh.v = *(const float4*)&boh[u];
    b_o.v = make_float4(hx.a[0]+hh.a[0], hx.a[1]+hh.a[1], hx.a[2]+hh.a[2], hx.a[3]+hh.a[3]);

    #pragma unroll
    for (int j = 0; j < 4; ++j) {
        float iv = sigf(zi.a[j] + b_i.a[j]);
        float fv = sigf(zf.a[j] + b_f.a[j]);
        float gv = tanhf(zg.a[j] + b_g.a[j]);
        float ov = sigf(zo.a[j] + b_o.a[j]);
        float cn = fv * cc.a[j] + iv * gv;
        cn4.a[j] = cn;
        hn4.a[j] = ov * tanhf(cn);
    }
    *(float4*)&out[e] = hn4.v;                                     // h_new
    *(float4*)&out[(size_t)BATCH * HS + e] = cn4.v;                // c_new
}

// ---------------- launcher ----------------
extern "C" void kernel_launch(void* const* d_in, const int* in_sizes, int n_in,
                              void* d_out, int out_size, void* d_ws, size_t ws_size,
                              hipStream_t stream)
{
    const float* x   = (const float*)d_in[0];
    const float* h   = (const float*)d_in[1];
    const float* c   = (const float*)d_in[2];
    const float* Wix = (const float*)d_in[3];  const float* bix = (const float*)d_in[4];
    const float* Wfx = (const float*)d_in[5];  const float* bfx = (const float*)d_in[6];
    const float* Wgx = (const float*)d_in[7];  const float* bgx = (const float*)d_in[8];
    const float* Wox = (const float*)d_in[9];  const float* box_ = (const float*)d_in[10];
    const float* Wih = (const float*)d_in[11]; const float* bih = (const float*)d_in[12];
    const float* Wfh = (const float*)d_in[13]; const float* bfh = (const float*)d_in[14];
    const float* Wgh = (const float*)d_in[15]; const float* bgh = (const float*)d_in[16];
    const float* Woh = (const float*)d_in[17]; const float* boh = (const float*)d_in[18];

    char* ws = (char*)d_ws;
    uint4* Apk = (uint4*)ws;                                   // 16 MB
    uint4* Bpk = (uint4*)(ws + (size_t)16 * 1024 * 1024);      // 16 MB
    float* z   = (float*)(ws + (size_t)32 * 1024 * 1024);      // 64 MB

    pack_kernel<<<8192, 256, 0, stream>>>(x, h, Wix, Wfx, Wgx, Wox,
                                          Wih, Wfh, Wgh, Woh, Apk, Bpk);
    gemm_kernel<<<256, 512, 0, stream>>>((const char*)Apk, (const char*)Bpk, z);
    epilogue_kernel<<<4096, 256, 0, stream>>>(z, c, bix, bfx, bgx, box_,
                                              bih, bfh, bgh, boh, (float*)d_out);
}

// Round 3
// 83.948 us; speedup vs baseline: 1.4781x; 1.2152x over previous
//
#include <hip/hip_runtime.h>
#include <hip/hip_bf16.h>
#include <stdint.h>

// ---------------- problem constants ----------------
#define BATCH  4096
#define IN_DIM 1024
#define HS     1024
#define K_DIM  2048                 // IN + HS
#define N_DIM  4096                 // 4 gates * HS (gate-interleaved, see pack)
#define BK 64
#define NKT (K_DIM / BK)            // 32 K-tiles
#define HALF_BYTES 16384            // 128 rows x 64 cols x 2B
#define TPB_BYTES  (NKT * HALF_BYTES)   // bytes per 128-row panel, all K

typedef __bf16 bf16x8 __attribute__((ext_vector_type(8)));
typedef float  f32x4  __attribute__((ext_vector_type(4)));

// ---------------- helpers ----------------
__device__ __forceinline__ unsigned short f2bf(float f) {
    union { float f; uint32_t u; } a; a.f = f;
    uint32_t r = a.u + 0x7FFF + ((a.u >> 16) & 1);   // RNE
    return (unsigned short)(r >> 16);
}
__device__ __forceinline__ uint32_t pk2(float a, float b) {
    return (uint32_t)f2bf(a) | ((uint32_t)f2bf(b) << 16);
}

__device__ __forceinline__ void load16_lds(const void* g, void* l) {
    __builtin_amdgcn_global_load_lds(
        (const __attribute__((address_space(1))) uint32_t*)g,
        (__attribute__((address_space(3))) uint32_t*)(uintptr_t)l,
        16, 0, 0);
}
// stage one 16KB half-tile: 512 threads x 16B x 2 rounds
__device__ __forceinline__ void stage16k(const char* g, char* l, int wid, int lane) {
    load16_lds(g + wid * 1024 + lane * 16,        l + wid * 1024);
    load16_lds(g + 8192 + wid * 1024 + lane * 16, l + 8192 + wid * 1024);
}

__device__ __forceinline__ float sigf(float x)  { return 1.0f / (1.0f + __expf(-x)); }
__device__ __forceinline__ float tanhf_(float x){ return 1.0f - 2.0f / (__expf(2.0f * x) + 1.0f); }

#define BAR()   __builtin_amdgcn_s_barrier()
#define LGKM0() do { asm volatile("s_waitcnt lgkmcnt(0)" ::: "memory"); \
                     __builtin_amdgcn_sched_barrier(0); } while (0)
#define DSB()   __builtin_amdgcn_sched_barrier(0)
#define PRIO(x) __builtin_amdgcn_s_setprio(x)

__device__ __forceinline__ void rdA(bf16x8 (&d)[4], const char* base, int kb) {
    #pragma unroll
    for (int i = 0; i < 4; ++i) d[i] = *(const bf16x8*)(base + i * 2048 + kb);
}
__device__ __forceinline__ void rdB(bf16x8 (&d)[4], const char* base, int kb) {
    #pragma unroll
    for (int i = 0; i < 4; ++i) d[i] = *(const bf16x8*)(base + i * 2048 + kb);
}
__device__ __forceinline__ void mfma16(f32x4 (&acc)[8][4], int mh,
                                       const bf16x8 (&a)[4], const bf16x8 (&b)[4]) {
    #pragma unroll
    for (int i = 0; i < 4; ++i)
        #pragma unroll
        for (int j = 0; j < 4; ++j)
            acc[mh * 4 + i][j] = __builtin_amdgcn_mfma_f32_16x16x32_bf16(
                a[i], b[j], acc[mh * 4 + i][j], 0, 0, 0);
}

// ---------------- kernel 1: pack A=[x|h], B gate-INTERLEAVED ----------------
// Packed B column n' -> gate q=(n'>>4)&3, unit u=((n'>>6)<<4)|(n'&15), so the
// GEMM fragment (col = base + j*16 + fr) maps j -> gate, (bn,wn,fr) -> unit.
__global__ void pack_kernel(const float* __restrict__ x, const float* __restrict__ h,
                            const float* __restrict__ Wix, const float* __restrict__ Wfx,
                            const float* __restrict__ Wgx, const float* __restrict__ Wox,
                            const float* __restrict__ Wih, const float* __restrict__ Wfh,
                            const float* __restrict__ Wgh, const float* __restrict__ Woh,
                            uint4* __restrict__ Apk, uint4* __restrict__ Bpk)
{
    int t = blockIdx.x * blockDim.x + threadIdx.x;     // 0 .. 2M-1
    const int NCHUNK = (BATCH * K_DIM) / 8;            // 1,048,576 chunks / matrix
    bool isB = t >= NCHUNK;
    int ci = isB ? (t - NCHUNK) : t;

    int cb  = ci & 7;              // 16B chunk within row (8 bf16)
    int row = (ci >> 3) & 127;     // row within 128-row panel
    int kt  = (ci >> 10) & 31;     // K-tile
    int bt  = ci >> 15;            // 128-row panel index, 0..31

    // inverse swizzle: chunk cb of LDS row holds source chunk cb ^ (row&7)
    int k0 = kt * BK + ((cb ^ (row & 7)) << 3);        // source k element, %8==0
    int gr = bt * 128 + row;                           // global m or packed col n'

    const float* src;
    if (!isB) {
        src = (k0 < IN_DIM) ? (x + (size_t)gr * IN_DIM + k0)
                            : (h + (size_t)gr * HS + (k0 - IN_DIM));
    } else {
        int q = (gr >> 4) & 3;                         // gate
        int u = ((gr >> 6) << 4) | (gr & 15);          // unit
        const float* Wq = (k0 < IN_DIM)
            ? ((q == 0) ? Wix : (q == 1) ? Wfx : (q == 2) ? Wgx : Wox)
            : ((q == 0) ? Wih : (q == 1) ? Wfh : (q == 2) ? Wgh : Woh);
        int kk = (k0 < IN_DIM) ? k0 : (k0 - IN_DIM);
        src = Wq + (size_t)u * 1024 + kk;
    }
    float4 v0 = ((const float4*)src)[0];
    float4 v1 = ((const float4*)src)[1];
    uint4 o;
    o.x = pk2(v0.x, v0.y); o.y = pk2(v0.z, v0.w);
    o.z = pk2(v1.x, v1.y); o.w = pk2(v1.z, v1.w);
    (isB ? Bpk : Apk)[ci] = o;
}

// ---------------- kernel 2: fused GEMM + LSTM gates ----------------
// 256x256 tile, 8 waves (2Mx4N), pipelined 4-phase K-loop:
//   phase p: lgkmcnt(0) [waits reads issued in p-1]; issue reads for p+1;
//            issue 1 stage; [p2 only: vmcnt(2)]; 16 MFMA; s_barrier.
// Race proof: every ds_read of a region completes (per-wave lgkmcnt(0))
// >=2 barriers before any wave ISSUES the global_load_lds overwriting it;
// cross-tile read prefetch (R0' at p3) is covered by vmcnt(2)@p2 + barrier
// (all waves' A(kt+1)/B(kt+1) stages landed). vmcnt never 0 in steady state.
__global__ void __launch_bounds__(512, 2)
gemm_kernel(const char* __restrict__ Apk, const char* __restrict__ Bpk,
            const float* __restrict__ c,
            const float* __restrict__ bix, const float* __restrict__ bfx,
            const float* __restrict__ bgx, const float* __restrict__ box_,
            const float* __restrict__ bih, const float* __restrict__ bfh,
            const float* __restrict__ bgh, const float* __restrict__ boh,
            float* __restrict__ out)
{
    __shared__ uint4 lds4[131072 / 16];                // 128 KiB
    char* lds = (char*)lds4;

    const int tid  = threadIdx.x;
    const int lane = tid & 63;
    const int wid  = tid >> 6;       // 0..7
    const int wm   = wid >> 2;       // 0..1
    const int wn   = wid & 3;        // 0..3
    const int fr   = lane & 15;
    const int kg   = lane >> 4;

    // XCD-aware bijective swizzle: 256 blocks, 8 XCDs, 32 blocks/XCD chunk
    const int phys = blockIdx.x;
    const int virt = (phys & 7) * 32 + (phys >> 3);
    const int bn   = virt & 15;
    const int bm   = virt >> 4;

    const char* gA = Apk + (size_t)(bm * 2) * TPB_BYTES;
    const char* gB = Bpk + (size_t)(bn * 2) * TPB_BYTES;

    // ds_read addressing (swizzle: k-byte ^ ((row&7)<<4); row%8 == fr%8)
    const int sw  = (fr & 7) << 4;
    const int kb0 = (kg * 16) ^ sw;                 // ks=0
    const int kb1 = (64 + kg * 16) ^ sw;            // ks=1
    const int aB  = wm * HALF_BYTES + fr * 128;     // A: half index == wm
    const int bB  = 32768 + (wn >> 1) * HALF_BYTES + ((wn & 1) * 64 + fr) * 128;

    f32x4 acc[8][4] = {};
    bf16x8 aX[4], aY[4], b0[4], b1[4];

    // ---- prologue: tile 0 (A0,A1,B0,B1) + tile 1 (B0,B1); then R0(tile0) ----
    stage16k(gA + (size_t)(0 * NKT + 0) * HALF_BYTES, lds + 0,     wid, lane);
    stage16k(gA + (size_t)(1 * NKT + 0) * HALF_BYTES, lds + 16384, wid, lane);
    stage16k(gB + (size_t)(0 * NKT + 0) * HALF_BYTES, lds + 32768, wid, lane);
    stage16k(gB + (size_t)(1 * NKT + 0) * HALF_BYTES, lds + 49152, wid, lane);
    stage16k(gB + (size_t)(0 * NKT + 1) * HALF_BYTES, lds + 65536 + 32768, wid, lane);
    stage16k(gB + (size_t)(1 * NKT + 1) * HALF_BYTES, lds + 65536 + 49152, wid, lane);
    asm volatile("s_waitcnt vmcnt(4)" ::: "memory");   // tile0 landed; tile1-B in flight
    BAR();
    rdA(aX, lds + aB, kb0);                            // R0: A-h0 ks0
    rdB(b0, lds + bB, kb0);                            //     B    ks0

    for (int kt = 0; kt < NKT; ++kt) {
        char* L  = lds + (kt & 1) * 65536;
        char* Ln = lds + ((kt & 1) ^ 1) * 65536;
        const bool s1 = (kt + 1 < NKT), s2 = (kt + 2 < NKT);

        // ---- phase 0: compute (mh0,ks0) on aX,b0; prefetch R1; stage A-h0(kt+1)
        LGKM0();
        rdA(aY, L + aB, kb1);                          // R1: A-h0 ks1
        rdB(b1, L + bB, kb1);                          //     B    ks1
        if (s1) stage16k(gA + (size_t)(0 * NKT + kt + 1) * HALF_BYTES, Ln + 0, wid, lane);
        DSB();
        PRIO(1); mfma16(acc, 0, aX, b0); PRIO(0);
        BAR();

        // ---- phase 1: compute (mh0,ks1) on aY,b1; prefetch R2; stage A-h1(kt+1)
        LGKM0();
        rdA(aX, L + aB + 8192, kb0);                   // R2: A-h1 ks0
        if (s1) stage16k(gA + (size_t)(1 * NKT + kt + 1) * HALF_BYTES, Ln + 16384, wid, lane);
        DSB();
        PRIO(1); mfma16(acc, 0, aY, b1); PRIO(0);
        BAR();

        // ---- phase 2: compute (mh1,ks0) on aX,b0; prefetch R3; stage B-h0(kt+2);
        //      vmcnt(2): all A(kt+1)/B(kt+1) landed, leaves B-h0(kt+2) in flight
        LGKM0();
        rdA(aY, L + aB + 8192, kb1);                   // R3: A-h1 ks1
        if (s2) stage16k(gB + (size_t)(0 * NKT + kt + 2) * HALF_BYTES, L + 32768, wid, lane);
        if (kt < NKT - 2)       asm volatile("s_waitcnt vmcnt(2)" ::: "memory");
        else if (kt == NKT - 2) asm volatile("s_waitcnt vmcnt(0)" ::: "memory");
        DSB();
        PRIO(1); mfma16(acc, 1, aX, b0); PRIO(0);
        BAR();

        // ---- phase 3: compute (mh1,ks1) on aY,b1; stage B-h1(kt+2);
        //      cross-tile prefetch R0'(kt+1) -> aX,b0 (safe per vmcnt(2)@p2+BAR)
        LGKM0();
        if (s2) stage16k(gB + (size_t)(1 * NKT + kt + 2) * HALF_BYTES, L + 49152, wid, lane);
        if (s1) { rdA(aX, Ln + aB, kb0); rdB(b0, Ln + bB, kb0); }
        DSB();
        PRIO(1); mfma16(acc, 1, aY, b1); PRIO(0);
        BAR();
    }

    // ---- fused LSTM epilogue: lane holds all 4 gates of unit u, rows of acc
    const int u  = bn * 64 + wn * 16 + fr;             // unit 0..1023
    const int r0 = bm * 256 + wm * 128;                // batch row base
    const float bi = bix[u] + bih[u];
    const float bf = bfx[u] + bfh[u];
    const float bg = bgx[u] + bgh[u];
    const float bo = box_[u] + boh[u];
    float* hout = out;
    float* cout = out + (size_t)BATCH * HS;

    #pragma unroll
    for (int ai = 0; ai < 8; ++ai) {
        const int rowb = r0 + ai * 16 + kg * 4;
        #pragma unroll
        for (int r = 0; r < 4; ++r) {
            const size_t idx = (size_t)(rowb + r) * HS + u;
            float iv = sigf  (acc[ai][0][r] + bi);
            float fv = sigf  (acc[ai][1][r] + bf);
            float gv = tanhf_(acc[ai][2][r] + bg);
            float ov = sigf  (acc[ai][3][r] + bo);
            float cn = fv * c[idx] + iv * gv;
            hout[idx] = ov * tanhf_(cn);
            cout[idx] = cn;
        }
    }
}

// ---------------- launcher ----------------
extern "C" void kernel_launch(void* const* d_in, const int* in_sizes, int n_in,
                              void* d_out, int out_size, void* d_ws, size_t ws_size,
                              hipStream_t stream)
{
    const float* x   = (const float*)d_in[0];
    const float* h   = (const float*)d_in[1];
    const float* c   = (const float*)d_in[2];
    const float* Wix = (const float*)d_in[3];  const float* bix = (const float*)d_in[4];
    const float* Wfx = (const float*)d_in[5];  const float* bfx = (const float*)d_in[6];
    const float* Wgx = (const float*)d_in[7];  const float* bgx = (const float*)d_in[8];
    const float* Wox = (const float*)d_in[9];  const float* box_ = (const float*)d_in[10];
    const float* Wih = (const float*)d_in[11]; const float* bih = (const float*)d_in[12];
    const float* Wfh = (const float*)d_in[13]; const float* bfh = (const float*)d_in[14];
    const float* Wgh = (const float*)d_in[15]; const float* bgh = (const float*)d_in[16];
    const float* Woh = (const float*)d_in[17]; const float* boh = (const float*)d_in[18];

    char* ws = (char*)d_ws;
    uint4* Apk = (uint4*)ws;                                   // 16 MB
    uint4* Bpk = (uint4*)(ws + (size_t)16 * 1024 * 1024);      // 16 MB

    pack_kernel<<<8192, 256, 0, stream>>>(x, h, Wix, Wfx, Wgx, Wox,
                                          Wih, Wfh, Wgh, Woh, Apk, Bpk);
    gemm_kernel<<<256, 512, 0, stream>>>((const char*)Apk, (const char*)Bpk, c,
                                         bix, bfx, bgx, box_, bih, bfh, bgh, boh,
                                         (float*)d_out);
}